// Round 5
// baseline (2577.999 us; speedup 1.0000x reference)
//
#include <hip/hip_runtime.h>
#include <hip/hip_bf16.h>

#define T_ 2048
#define B_ 1024
#define H_ 256
#define I_ 8
#define A_ 8
#define DT_ 0.1f
#define EPS_ 1e-5f
#define LSTR 296  // bf16 elems per h_lds row
#define CH 32     // x-staging chunk (timesteps)

typedef __attribute__((ext_vector_type(8))) short bf16x8;
typedef __attribute__((ext_vector_type(4))) float f32x4;

#if __has_builtin(__builtin_amdgcn_cvt_pk_bf16_f32)
typedef __attribute__((ext_vector_type(2))) __bf16 bf16x2;
__device__ __forceinline__ int pk2bf(float a, float b) {
    bf16x2 r = __builtin_amdgcn_cvt_pk_bf16_f32(a, b);
    return __builtin_bit_cast(int, r);
}
#else
__device__ __forceinline__ short f2bf1(float f) {
    unsigned u = __builtin_bit_cast(unsigned, f);
    u += 0x7fffu + ((u >> 16) & 1u);   // RNE
    return (short)(u >> 16);
}
__device__ __forceinline__ int pk2bf(float a, float b) {
    return (int)(unsigned short)f2bf1(a) | ((int)f2bf1(b) << 16);
}
#endif

__launch_bounds__(256, 1)
__global__ void liquid_kernel(const float* __restrict__ x,
                              const float* __restrict__ W_in,
                              const float* __restrict__ b_in,
                              const float* __restrict__ tau_param,
                              const float* __restrict__ W_rec,
                              const float* __restrict__ g1,
                              const float* __restrict__ beta1,
                              const float* __restrict__ g2,
                              const float* __restrict__ beta2,
                              const float* __restrict__ head_w,
                              const float* __restrict__ head_b,
                              float* __restrict__ out) {
    __shared__ short  h_lds[16 * LSTR];          // h_t (bf16), cols 0..255 used
    __shared__ short  xstage[2][CH][16][8];      // x chunks (bf16), [buf][t][row][i]
    __shared__ alignas(16) int zero16[4];        // zero B-frag for quads 1-3 at ks=8
    __shared__ alignas(16) float2 redt[16][6];   // LN partials [row][wave(4)+pad]
    __shared__ float  hw[H_ * A_];               // head_w staging
    __shared__ float  outp[4][16][A_];           // epilogue head partials

    const int tid  = threadIdx.x;
    const int w    = tid >> 6;    // wave 0..3 -> owns s-cols [w*64, w*64+64)
    const int lane = tid & 63;
    const int quad = lane >> 4;
    const int l15  = lane & 15;   // batch-row within block
    const int r0   = blockIdx.x * 16;

    // ---- zero LDS state ----
    for (int i = tid; i < 16 * LSTR; i += 256) h_lds[i] = 0;
    if (tid < 4) zero16[tid] = 0;

    // ---- per-lane params for owned s-cols: c = w*64 + mt*16 + quad*4 + r ----
    f32x4 pbin[4];                 // MFMA C-seed (loop-invariant registers)
    float p_g1s[16], p_b1s[16], p_decay[16];
#pragma unroll
    for (int mt = 0; mt < 4; ++mt)
#pragma unroll
        for (int r = 0; r < 4; ++r) {
            int c = w * 64 + mt * 16 + quad * 4 + r;
            int s = mt * 4 + r;
            pbin[mt][r] = b_in[c];
            p_g1s[s] = g1[c] * 2.885390082f;     // fold tanh's 2/ln2 scale
            p_b1s[s] = beta1[c] * 2.885390082f;
            float tp = tau_param[c];
            float sp = (tp > 20.f) ? tp : log1pf(expf(tp));  // softplus
            p_decay[s] = 1.0f - DT_ / sp;
        }

    // ---- A fragments resident in regs: A[m=l15][k=quad*8+j] = W_ext[k][cA] ----
    // W_ext rows 0..255 = W_rec, 256..263 = W_in, 264..287 = 0
    bf16x8 afrag[4][9];
#pragma unroll
    for (int mt = 0; mt < 4; ++mt) {
        int cA = w * 64 + mt * 16 + l15;
#pragma unroll
        for (int ks = 0; ks < 9; ++ks) {
            bf16x8 f;
#pragma unroll
            for (int j = 0; j < 8; ++j) {
                int kg = ks * 32 + quad * 8 + j;
                float v;
                if (kg < 256)      v = W_rec[kg * H_ + cA];
                else if (kg < 264) v = W_in[(kg - 256) * H_ + cA];
                else               v = 0.f;
                f[j] = (short)pk2bf(v, v);
            }
            afrag[mt][ks] = f;
        }
    }

    // ---- x chunk loader: thread owns row=tid>>4, 4 float4 per chunk, coalesced ----
    const int xrow = tid >> 4, xl = tid & 15;
    const float* xrbase = x + (size_t)(r0 + xrow) * T_ * I_;
    float4 xr[4];

    // chunk 0: load + convert + store (pre-loop, before first barrier)
#pragma unroll
    for (int j = 0; j < 4; ++j) xr[j] = ((const float4*)xrbase)[xl + 16 * j];
#pragma unroll
    for (int j = 0; j < 4; ++j) {
        int f4 = xl + 16 * j;              // float4 idx within row-chunk (0..63)
        int tl = f4 >> 1, i0 = (f4 & 1) * 4;
        int2 pk = make_int2(pk2bf(xr[j].x, xr[j].y), pk2bf(xr[j].z, xr[j].w));
        *reinterpret_cast<int2*>(&xstage[0][tl][xrow][i0]) = pk;
    }
    // issue chunk 1 loads (converted at t=16)
#pragma unroll
    for (int j = 0; j < 4; ++j) xr[j] = ((const float4*)(xrbase + (size_t)CH * I_))[xl + 16 * j];

    float hreg[16];
#pragma unroll
    for (int s = 0; s < 16; ++s) hreg[s] = 0.f;

    const short* hrow = &h_lds[l15 * LSTR + quad * 8];

    for (int t = 0; t < T_; ++t) {
        const int tc  = t & (CH - 1);
        const int c   = t >> 5;
        const int buf = c & 1;

        __syncthreads();  // barrier #1: h_t visible

        if (tc == 16) {   // convert held regs (chunk c+1) into idle buffer
#pragma unroll
            for (int j = 0; j < 4; ++j) {
                int f4 = xl + 16 * j;
                int tl = f4 >> 1, i0 = (f4 & 1) * 4;
                int2 pk = make_int2(pk2bf(xr[j].x, xr[j].y), pk2bf(xr[j].z, xr[j].w));
                *reinterpret_cast<int2*>(&xstage[buf ^ 1][tl][xrow][i0]) = pk;
            }
        }
        if (tc == 18) {   // issue loads for chunk c+2 (consumed ~46 steps later)
            int cc = c + 2; if (cc > (T_ / CH) - 1) cc = (T_ / CH) - 1;
            const float4* src = (const float4*)(xrbase + (size_t)cc * CH * I_);
#pragma unroll
            for (int j = 0; j < 4; ++j) xr[j] = src[xl + 16 * j];
        }

        // ---- GEMM: 4 chains (one per mt), C seeded from loop-invariant pbin ----
        const short* xb = (quad == 0) ? &xstage[buf][tc][l15][0] : (const short*)zero16;
        f32x4 acc[4];
        {
            bf16x8 b0 = *reinterpret_cast<const bf16x8*>(hrow);
#pragma unroll
            for (int mt = 0; mt < 4; ++mt)
                acc[mt] = __builtin_amdgcn_mfma_f32_16x16x32_bf16(afrag[mt][0], b0, pbin[mt], 0, 0, 0);
        }
#pragma unroll
        for (int ks = 1; ks < 8; ++ks) {
            bf16x8 bfr = *reinterpret_cast<const bf16x8*>(hrow + ks * 32);
#pragma unroll
            for (int mt = 0; mt < 4; ++mt)
                acc[mt] = __builtin_amdgcn_mfma_f32_16x16x32_bf16(afrag[mt][ks], bfr, acc[mt], 0, 0, 0);
        }
        {
            bf16x8 b8 = *reinterpret_cast<const bf16x8*>(xb);
#pragma unroll
            for (int mt = 0; mt < 4; ++mt)
                acc[mt] = __builtin_amdgcn_mfma_f32_16x16x32_bf16(afrag[mt][8], b8, acc[mt], 0, 0, 0);
        }

        // ---- LN partial: balanced in-lane fold + 2 shfl, write per-wave partial ----
        float s0 = (acc[0][0] + acc[0][1]) + (acc[0][2] + acc[0][3]);
        float s1 = (acc[1][0] + acc[1][1]) + (acc[1][2] + acc[1][3]);
        float s2 = (acc[2][0] + acc[2][1]) + (acc[2][2] + acc[2][3]);
        float s3 = (acc[3][0] + acc[3][1]) + (acc[3][2] + acc[3][3]);
        float S  = (s0 + s1) + (s2 + s3);
        float q0 = fmaf(acc[0][0], acc[0][0], fmaf(acc[0][1], acc[0][1],
                   fmaf(acc[0][2], acc[0][2], acc[0][3] * acc[0][3])));
        float q1 = fmaf(acc[1][0], acc[1][0], fmaf(acc[1][1], acc[1][1],
                   fmaf(acc[1][2], acc[1][2], acc[1][3] * acc[1][3])));
        float q2 = fmaf(acc[2][0], acc[2][0], fmaf(acc[2][1], acc[2][1],
                   fmaf(acc[2][2], acc[2][2], acc[2][3] * acc[2][3])));
        float q3 = fmaf(acc[3][0], acc[3][0], fmaf(acc[3][1], acc[3][1],
                   fmaf(acc[3][2], acc[3][2], acc[3][3] * acc[3][3])));
        float SQ = (q0 + q1) + (q2 + q3);
        S += __shfl_xor(S, 16, 64);  SQ += __shfl_xor(SQ, 16, 64);
        S += __shfl_xor(S, 32, 64);  SQ += __shfl_xor(SQ, 32, 64);
        if (quad == 0) redt[l15][w] = make_float2(S, SQ);

        __syncthreads();  // barrier #2: all wave partials in redt

        // ---- final stats: 2x ds_read_b128 (4 wave partials) ----
        const float4* rrow = reinterpret_cast<const float4*>(&redt[l15][0]);
        float4 ra = rrow[0], rb = rrow[1];
        float St  = (ra.x + ra.z) + (rb.x + rb.z);
        float SQt = (ra.y + ra.w) + (rb.y + rb.w);
        const float mu   = St * (1.f / 256.f);
        const float var  = fmaf(SQt, 1.f / 256.f, -mu * mu);
        const float rstd = __builtin_amdgcn_rsqf(var + EPS_);
        const float nmr  = -mu * rstd;

        // ---- f = tanh(LN*g1+b1); h = med3(h*decay + DT*f) ----
#pragma unroll
        for (int s = 0; s < 16; ++s) {
            float v  = acc[s >> 2][s & 3];
            float tt = fmaf(v, rstd, nmr);
            float z2 = fmaf(tt, p_g1s[s], p_b1s[s]);            // 2z/ln2
            float e  = __builtin_amdgcn_exp2f(z2);              // e^(2z)
            float rc = __builtin_amdgcn_rcpf(e + 1.f);
            float fd = fmaf(rc, -2.f * DT_, DT_);               // DT*tanh(z)
            float h  = fmaf(hreg[s], p_decay[s], fd);
            hreg[s]  = __builtin_amdgcn_fmed3f(h, -10.f, 10.f);
        }
#pragma unroll
        for (int mt = 0; mt < 4; ++mt) {
            int2 pk = make_int2(pk2bf(hreg[mt * 4 + 0], hreg[mt * 4 + 1]),
                                pk2bf(hreg[mt * 4 + 2], hreg[mt * 4 + 3]));
            *reinterpret_cast<int2*>(&h_lds[l15 * LSTR + w * 64 + mt * 16 + quad * 4]) = pk;
        }
    }

    // ---- epilogue: out = LN(h_T; g2,b2) @ head_w + head_b ----
    for (int i = tid; i < H_ * A_; i += 256) hw[i] = head_w[i];
    __syncthreads();

    float S2 = 0.f, SQ2 = 0.f;
#pragma unroll
    for (int s = 0; s < 16; ++s) { S2 += hreg[s]; SQ2 = fmaf(hreg[s], hreg[s], SQ2); }
    S2 += __shfl_xor(S2, 16, 64);  SQ2 += __shfl_xor(SQ2, 16, 64);
    S2 += __shfl_xor(S2, 32, 64);  SQ2 += __shfl_xor(SQ2, 32, 64);
    if (quad == 0) redt[l15][w] = make_float2(S2, SQ2);
    __syncthreads();
    const float4* rrow = reinterpret_cast<const float4*>(&redt[l15][0]);
    float4 ra = rrow[0], rb = rrow[1];
    float St  = (ra.x + ra.z) + (rb.x + rb.z);
    float SQt = (ra.y + ra.w) + (rb.y + rb.w);
    const float mu   = St * (1.f / 256.f);
    const float var  = fmaf(SQt, 1.f / 256.f, -mu * mu);
    const float rstd = __builtin_amdgcn_rsqf(var + EPS_);

    float pa[8];
#pragma unroll
    for (int a = 0; a < 8; ++a) pa[a] = 0.f;
#pragma unroll
    for (int s = 0; s < 16; ++s) {
        int c = w * 64 + (s >> 2) * 16 + quad * 4 + (s & 3);
        float lnh = (hreg[s] - mu) * rstd * g2[c] + beta2[c];
        float4 w0 = *reinterpret_cast<const float4*>(&hw[c * 8]);
        float4 w1 = *reinterpret_cast<const float4*>(&hw[c * 8 + 4]);
        pa[0] += lnh * w0.x; pa[1] += lnh * w0.y; pa[2] += lnh * w0.z; pa[3] += lnh * w0.w;
        pa[4] += lnh * w1.x; pa[5] += lnh * w1.y; pa[6] += lnh * w1.z; pa[7] += lnh * w1.w;
    }
#pragma unroll
    for (int a = 0; a < 8; ++a) {
        pa[a] += __shfl_xor(pa[a], 16, 64);
        pa[a] += __shfl_xor(pa[a], 32, 64);
    }
    if (quad == 0) {
#pragma unroll
        for (int a = 0; a < 8; ++a) outp[w][l15][a] = pa[a];
    }
    __syncthreads();
    if (tid < 128) {
        int r = tid >> 3, a = tid & 7;
        float s = head_b[a];
#pragma unroll
        for (int ww = 0; ww < 4; ++ww) s += outp[ww][r][a];
        out[(size_t)(r0 + r) * A_ + a] = s;
    }
}

extern "C" void kernel_launch(void* const* d_in, const int* in_sizes, int n_in,
                              void* d_out, int out_size, void* d_ws, size_t ws_size,
                              hipStream_t stream) {
    const float* x         = (const float*)d_in[0];
    const float* W_in      = (const float*)d_in[1];
    const float* b_in      = (const float*)d_in[2];
    const float* tau_param = (const float*)d_in[3];
    const float* W_rec     = (const float*)d_in[4];
    const float* g1        = (const float*)d_in[5];
    const float* beta1     = (const float*)d_in[6];
    const float* g2        = (const float*)d_in[7];
    const float* beta2     = (const float*)d_in[8];
    const float* head_w    = (const float*)d_in[9];
    const float* head_b    = (const float*)d_in[10];
    float* out = (float*)d_out;

    liquid_kernel<<<64, 256, 0, stream>>>(x, W_in, b_in, tau_param, W_rec,
                                          g1, beta1, g2, beta2, head_w, head_b, out);
}

// Round 6
// 2336.794 us; speedup vs baseline: 1.1032x; 1.1032x over previous
//
#include <hip/hip_runtime.h>
#include <hip/hip_bf16.h>

#define T_ 2048
#define B_ 1024
#define H_ 256
#define I_ 8
#define A_ 8
#define DT_ 0.1f
#define EPS_ 1e-5f
#define LSTR 296  // bf16 elems per h_lds row
#define CH 32     // x-staging chunk (timesteps)
#define RB 8      // real batch rows per block

typedef __attribute__((ext_vector_type(8))) short bf16x8;
typedef __attribute__((ext_vector_type(4))) float f32x4;

#if __has_builtin(__builtin_amdgcn_cvt_pk_bf16_f32)
typedef __attribute__((ext_vector_type(2))) __bf16 bf16x2;
__device__ __forceinline__ int pk2bf(float a, float b) {
    bf16x2 r = __builtin_amdgcn_cvt_pk_bf16_f32(a, b);
    return __builtin_bit_cast(int, r);
}
#else
__device__ __forceinline__ short f2bf1(float f) {
    unsigned u = __builtin_bit_cast(unsigned, f);
    u += 0x7fffu + ((u >> 16) & 1u);   // RNE
    return (short)(u >> 16);
}
__device__ __forceinline__ int pk2bf(float a, float b) {
    return (int)(unsigned short)f2bf1(a) | ((int)f2bf1(b) << 16);
}
#endif

__launch_bounds__(512, 2)
__global__ void liquid_kernel(const float* __restrict__ x,
                              const float* __restrict__ W_in,
                              const float* __restrict__ b_in,
                              const float* __restrict__ tau_param,
                              const float* __restrict__ W_rec,
                              const float* __restrict__ g1,
                              const float* __restrict__ beta1,
                              const float* __restrict__ g2,
                              const float* __restrict__ beta2,
                              const float* __restrict__ head_w,
                              const float* __restrict__ head_b,
                              float* __restrict__ out) {
    __shared__ short  h_lds[16 * LSTR];          // h_t (bf16); rows 8..15 stay zero (pad rows)
    __shared__ short  xstage[2][CH][RB][8];      // x chunks (bf16), [buf][t][row][i]
    __shared__ alignas(16) int zero16[4];        // zero B-frag (pad lanes / quads 1-3 at ks=8)
    __shared__ alignas(16) float2 redt[16][10];  // LN partials [row][wave(8)+pad]
    __shared__ float  hw[H_ * A_];               // head_w staging
    __shared__ float  outp[8][RB][A_];           // epilogue head partials

    const int tid  = threadIdx.x;
    const int w    = tid >> 6;    // wave 0..7 -> owns s-cols [w*32, w*32+32)
    const int lane = tid & 63;
    const int quad = lane >> 4;
    const int l15  = lane & 15;   // batch-row within block (rows >= RB are pad)
    const int r0   = blockIdx.x * RB;

    // ---- zero LDS state ----
    for (int i = tid; i < 16 * LSTR; i += 512) h_lds[i] = 0;
    if (tid < 4) zero16[tid] = 0;

    // ---- per-lane params for owned s-cols: c = w*32 + mt*16 + quad*4 + r ----
    f32x4 pbin[2];
    float p_g1s[8], p_b1s[8], p_decay[8];
#pragma unroll
    for (int mt = 0; mt < 2; ++mt)
#pragma unroll
        for (int r = 0; r < 4; ++r) {
            int c = w * 32 + mt * 16 + quad * 4 + r;
            int s = mt * 4 + r;
            pbin[mt][r] = b_in[c];
            p_g1s[s] = g1[c] * 2.885390082f;     // fold tanh's 2/ln2 scale
            p_b1s[s] = beta1[c] * 2.885390082f;
            float tp = tau_param[c];
            float sp = (tp > 20.f) ? tp : log1pf(expf(tp));  // softplus
            p_decay[s] = 1.0f - DT_ / sp;
        }

    // ---- A fragments resident in regs: A[m=l15][k=quad*8+j] = W_ext[k][cA] ----
    // W_ext rows 0..255 = W_rec, 256..263 = W_in, 264..287 = 0
    bf16x8 afrag[2][9];
#pragma unroll
    for (int mt = 0; mt < 2; ++mt) {
        int cA = w * 32 + mt * 16 + l15;
#pragma unroll
        for (int ks = 0; ks < 9; ++ks) {
            bf16x8 f;
#pragma unroll
            for (int j = 0; j < 8; ++j) {
                int kg = ks * 32 + quad * 8 + j;
                float v;
                if (kg < 256)      v = W_rec[kg * H_ + cA];
                else if (kg < 264) v = W_in[(kg - 256) * H_ + cA];
                else               v = 0.f;
                f[j] = (short)pk2bf(v, v);
            }
            afrag[mt][ks] = f;
        }
    }

    // ---- x chunk loader: wave w loads row w (one float4/lane/chunk, coalesced) ----
    // chunk layout per row: 32 t x 8 i = 64 float4; lane = f4 idx; t=lane>>1, i0=(lane&1)*4
    const float* xrbase = x + (size_t)(r0 + w) * T_ * I_;
    const int xt = lane >> 1, xi0 = (lane & 1) * 4;
    float4 xr;

    // chunk 0: load + convert + store (pre-loop)
    xr = ((const float4*)xrbase)[lane];
    {
        int2 pk = make_int2(pk2bf(xr.x, xr.y), pk2bf(xr.z, xr.w));
        *reinterpret_cast<int2*>(&xstage[0][xt][w][xi0]) = pk;
    }
    // issue chunk 1 loads (converted at t=16)
    xr = ((const float4*)(xrbase + (size_t)CH * I_))[lane];

    float hreg[8];
#pragma unroll
    for (int s = 0; s < 8; ++s) hreg[s] = 0.f;

    const short* hrow = &h_lds[l15 * LSTR + quad * 8];
    const f32x4 zacc = {0.f, 0.f, 0.f, 0.f};

    for (int t = 0; t < T_; ++t) {
        const int tc  = t & (CH - 1);
        const int c   = t >> 5;
        const int buf = c & 1;

        __syncthreads();  // barrier #1: h_t visible

        if (tc == 16) {   // convert held regs (chunk c+1) into idle buffer
            int2 pk = make_int2(pk2bf(xr.x, xr.y), pk2bf(xr.z, xr.w));
            *reinterpret_cast<int2*>(&xstage[buf ^ 1][xt][w][xi0]) = pk;
        }
        if (tc == 18) {   // issue loads for chunk c+2 (consumed ~30 steps later)
            int cc = c + 2; if (cc > (T_ / CH) - 1) cc = (T_ / CH) - 1;
            xr = ((const float4*)(xrbase + (size_t)cc * CH * I_))[lane];
        }

        // ---- GEMM: 4 chains (2 mt x 2 k-halves), dep depth 5/4 ----
        const short* xb = (quad == 0 && l15 < RB) ? &xstage[buf][tc][l15][0]
                                                  : (const short*)zero16;
        f32x4 c0a = pbin[0], c1a = pbin[1], c0b = zacc, c1b = zacc;
#pragma unroll
        for (int ks = 0; ks < 4; ++ks) {
            bf16x8 bA = *reinterpret_cast<const bf16x8*>(hrow + ks * 32);
            bf16x8 bB = *reinterpret_cast<const bf16x8*>(hrow + (ks + 4) * 32);
            c0a = __builtin_amdgcn_mfma_f32_16x16x32_bf16(afrag[0][ks],     bA, c0a, 0, 0, 0);
            c1a = __builtin_amdgcn_mfma_f32_16x16x32_bf16(afrag[1][ks],     bA, c1a, 0, 0, 0);
            c0b = __builtin_amdgcn_mfma_f32_16x16x32_bf16(afrag[0][ks + 4], bB, c0b, 0, 0, 0);
            c1b = __builtin_amdgcn_mfma_f32_16x16x32_bf16(afrag[1][ks + 4], bB, c1b, 0, 0, 0);
        }
        {
            bf16x8 b8 = *reinterpret_cast<const bf16x8*>(xb);
            c0a = __builtin_amdgcn_mfma_f32_16x16x32_bf16(afrag[0][8], b8, c0a, 0, 0, 0);
            c1a = __builtin_amdgcn_mfma_f32_16x16x32_bf16(afrag[1][8], b8, c1a, 0, 0, 0);
        }
        f32x4 acc0 = c0a + c0b, acc1 = c1a + c1b;

        // ---- LN partial: in-lane fold + 2 shfl, write per-wave partial ----
        float S  = ((acc0[0] + acc0[1]) + (acc0[2] + acc0[3]))
                 + ((acc1[0] + acc1[1]) + (acc1[2] + acc1[3]));
        float SQ = fmaf(acc0[0], acc0[0], fmaf(acc0[1], acc0[1],
                   fmaf(acc0[2], acc0[2], acc0[3] * acc0[3])))
                 + fmaf(acc1[0], acc1[0], fmaf(acc1[1], acc1[1],
                   fmaf(acc1[2], acc1[2], acc1[3] * acc1[3])));
        S += __shfl_xor(S, 16, 64);  SQ += __shfl_xor(SQ, 16, 64);
        S += __shfl_xor(S, 32, 64);  SQ += __shfl_xor(SQ, 32, 64);
        if (quad == 0) redt[l15][w] = make_float2(S, SQ);

        __syncthreads();  // barrier #2: all wave partials in redt

        // ---- final stats: 4x ds_read_b128 (8 wave partials) ----
        const float4* rrow = reinterpret_cast<const float4*>(&redt[l15][0]);
        float4 q0 = rrow[0], q1 = rrow[1], q2 = rrow[2], q3 = rrow[3];
        float St  = ((q0.x + q0.z) + (q1.x + q1.z)) + ((q2.x + q2.z) + (q3.x + q3.z));
        float SQt = ((q0.y + q0.w) + (q1.y + q1.w)) + ((q2.y + q2.w) + (q3.y + q3.w));
        const float mu   = St * (1.f / 256.f);
        const float var  = fmaf(SQt, 1.f / 256.f, -mu * mu);
        const float rstd = __builtin_amdgcn_rsqf(var + EPS_);
        const float nmr  = -mu * rstd;

        // ---- f = tanh(LN*g1+b1); h = med3(h*decay + DT*f) ----
#pragma unroll
        for (int s = 0; s < 8; ++s) {
            float v  = (s < 4) ? acc0[s] : acc1[s - 4];
            float tt = fmaf(v, rstd, nmr);
            float z2 = fmaf(tt, p_g1s[s], p_b1s[s]);            // 2z/ln2
            float e  = __builtin_amdgcn_exp2f(z2);              // e^(2z)
            float rc = __builtin_amdgcn_rcpf(e + 1.f);
            float fd = fmaf(rc, -2.f * DT_, DT_);               // DT*tanh(z)
            float h  = fmaf(hreg[s], p_decay[s], fd);
            hreg[s]  = __builtin_amdgcn_fmed3f(h, -10.f, 10.f);
        }
        if (l15 < RB) {
            int2 pk0 = make_int2(pk2bf(hreg[0], hreg[1]), pk2bf(hreg[2], hreg[3]));
            int2 pk1 = make_int2(pk2bf(hreg[4], hreg[5]), pk2bf(hreg[6], hreg[7]));
            *reinterpret_cast<int2*>(&h_lds[l15 * LSTR + w * 32 + quad * 4])      = pk0;
            *reinterpret_cast<int2*>(&h_lds[l15 * LSTR + w * 32 + 16 + quad * 4]) = pk1;
        }
    }

    // ---- epilogue: out = LN(h_T; g2,b2) @ head_w + head_b ----
    for (int i = tid; i < H_ * A_; i += 512) hw[i] = head_w[i];
    __syncthreads();

    float S2 = 0.f, SQ2 = 0.f;
#pragma unroll
    for (int s = 0; s < 8; ++s) { S2 += hreg[s]; SQ2 = fmaf(hreg[s], hreg[s], SQ2); }
    S2 += __shfl_xor(S2, 16, 64);  SQ2 += __shfl_xor(SQ2, 16, 64);
    S2 += __shfl_xor(S2, 32, 64);  SQ2 += __shfl_xor(SQ2, 32, 64);
    if (quad == 0) redt[l15][w] = make_float2(S2, SQ2);
    __syncthreads();
    const float4* rrow = reinterpret_cast<const float4*>(&redt[l15][0]);
    float4 q0 = rrow[0], q1 = rrow[1], q2 = rrow[2], q3 = rrow[3];
    float St  = ((q0.x + q0.z) + (q1.x + q1.z)) + ((q2.x + q2.z) + (q3.x + q3.z));
    float SQt = ((q0.y + q0.w) + (q1.y + q1.w)) + ((q2.y + q2.w) + (q3.y + q3.w));
    const float mu   = St * (1.f / 256.f);
    const float var  = fmaf(SQt, 1.f / 256.f, -mu * mu);
    const float rstd = __builtin_amdgcn_rsqf(var + EPS_);

    float pa[8];
#pragma unroll
    for (int a = 0; a < 8; ++a) pa[a] = 0.f;
#pragma unroll
    for (int s = 0; s < 8; ++s) {
        int c = w * 32 + (s >> 2) * 16 + quad * 4 + (s & 3);
        float lnh = (hreg[s] - mu) * rstd * g2[c] + beta2[c];
        float4 w0 = *reinterpret_cast<const float4*>(&hw[c * 8]);
        float4 w1 = *reinterpret_cast<const float4*>(&hw[c * 8 + 4]);
        pa[0] += lnh * w0.x; pa[1] += lnh * w0.y; pa[2] += lnh * w0.z; pa[3] += lnh * w0.w;
        pa[4] += lnh * w1.x; pa[5] += lnh * w1.y; pa[6] += lnh * w1.z; pa[7] += lnh * w1.w;
    }
#pragma unroll
    for (int a = 0; a < 8; ++a) {
        pa[a] += __shfl_xor(pa[a], 16, 64);
        pa[a] += __shfl_xor(pa[a], 32, 64);
    }
    if (quad == 0 && l15 < RB) {
#pragma unroll
        for (int a = 0; a < 8; ++a) outp[w][l15][a] = pa[a];
    }
    __syncthreads();
    if (tid < RB * A_) {
        int r = tid >> 3, a = tid & 7;
        float s = head_b[a];
#pragma unroll
        for (int ww = 0; ww < 8; ++ww) s += outp[ww][r][a];
        out[(size_t)(r0 + r) * A_ + a] = s;
    }
}

extern "C" void kernel_launch(void* const* d_in, const int* in_sizes, int n_in,
                              void* d_out, int out_size, void* d_ws, size_t ws_size,
                              hipStream_t stream) {
    const float* x         = (const float*)d_in[0];
    const float* W_in      = (const float*)d_in[1];
    const float* b_in      = (const float*)d_in[2];
    const float* tau_param = (const float*)d_in[3];
    const float* W_rec     = (const float*)d_in[4];
    const float* g1        = (const float*)d_in[5];
    const float* beta1     = (const float*)d_in[6];
    const float* g2        = (const float*)d_in[7];
    const float* beta2     = (const float*)d_in[8];
    const float* head_w    = (const float*)d_in[9];
    const float* head_b    = (const float*)d_in[10];
    float* out = (float*)d_out;

    liquid_kernel<<<128, 512, 0, stream>>>(x, W_in, b_in, tau_param, W_rec,
                                           g1, beta1, g2, beta2, head_w, head_b, out);
}

// Round 7
// 1971.234 us; speedup vs baseline: 1.3078x; 1.1854x over previous
//
#include <hip/hip_runtime.h>
#include <hip/hip_bf16.h>

#define T_ 2048
#define B_ 1024
#define H_ 256
#define I_ 8
#define A_ 8
#define DT_ 0.1f
#define EPS_ 1e-5f
#define LSTR 296  // bf16 elems per h_lds row
#define CH 32     // x-staging chunk (timesteps)
#define RB 8      // real batch rows per block

typedef __attribute__((ext_vector_type(8))) short bf16x8;
typedef __attribute__((ext_vector_type(4))) float f32x4;

#if __has_builtin(__builtin_amdgcn_cvt_pk_bf16_f32)
typedef __attribute__((ext_vector_type(2))) __bf16 bf16x2;
__device__ __forceinline__ int pk2bf(float a, float b) {
    bf16x2 r = __builtin_amdgcn_cvt_pk_bf16_f32(a, b);
    return __builtin_bit_cast(int, r);
}
#else
__device__ __forceinline__ short f2bf1(float f) {
    unsigned u = __builtin_bit_cast(unsigned, f);
    u += 0x7fffu + ((u >> 16) & 1u);   // RNE
    return (short)(u >> 16);
}
__device__ __forceinline__ int pk2bf(float a, float b) {
    return (int)(unsigned short)f2bf1(a) | ((int)f2bf1(b) << 16);
}
#endif

__launch_bounds__(512, 2)
__global__ void liquid_kernel(const float* __restrict__ x,
                              const float* __restrict__ W_in,
                              const float* __restrict__ b_in,
                              const float* __restrict__ tau_param,
                              const float* __restrict__ W_rec,
                              const float* __restrict__ g1,
                              const float* __restrict__ beta1,
                              const float* __restrict__ g2,
                              const float* __restrict__ beta2,
                              const float* __restrict__ head_w,
                              const float* __restrict__ head_b,
                              float* __restrict__ out) {
    __shared__ short  h_lds[RB * LSTR];          // h_t (bf16), 8 real rows only
    __shared__ short  xstage[2][CH][RB][8];      // x chunks (bf16), [buf][t][row][i]
    __shared__ alignas(16) int zero16[4];        // zero B-frag for quads 1-3 at ks=8
    __shared__ alignas(16) float2 redt[RB][10];  // LN partials [row][wave(8)+pad]
    __shared__ float  hw[H_ * A_];               // head_w staging
    __shared__ float  outp[8][RB][A_];           // epilogue head partials

    const int tid  = threadIdx.x;
    const int w    = tid >> 6;    // wave 0..7 -> owns s-cols [w*32, w*32+32)
    const int lane = tid & 63;
    const int quad = lane >> 4;
    const int l15  = lane & 15;
    const int row  = l15 & 7;     // batch-row within block (lanes l15>=8 alias row l15-8)
    const int half = l15 >> 3;    // 0: handles mt0 cols, 1: handles mt1 cols
    const int r0   = blockIdx.x * RB;

    // ---- zero LDS state ----
    for (int i = tid; i < RB * LSTR; i += 512) h_lds[i] = 0;
    if (tid < 4) zero16[tid] = 0;

    // ---- per-lane params: this lane's 4 owned cols c = w*32 + half*16 + quad*4 + r ----
    f32x4 pbin0, pbin1;               // MFMA C-seeds (both mt, loop-invariant)
    float p_g1s[4], p_b1s[4], p_decay[4];
#pragma unroll
    for (int r = 0; r < 4; ++r) {
        pbin0[r] = b_in[w * 32 + quad * 4 + r];
        pbin1[r] = b_in[w * 32 + 16 + quad * 4 + r];
        int c = w * 32 + half * 16 + quad * 4 + r;
        p_g1s[r] = g1[c] * 2.885390082f;     // fold tanh's 2/ln2 scale
        p_b1s[r] = beta1[c] * 2.885390082f;
        float tp = tau_param[c];
        float sp = (tp > 20.f) ? tp : log1pf(expf(tp));  // softplus
        p_decay[r] = 1.0f - DT_ / sp;
    }

    // ---- A fragments resident in regs: A[m=l15][k=quad*8+j] = W_ext[k][cA] ----
    // W_ext rows 0..255 = W_rec, 256..263 = W_in, 264..287 = 0
    bf16x8 afrag[2][9];
#pragma unroll
    for (int mt = 0; mt < 2; ++mt) {
        int cA = w * 32 + mt * 16 + l15;
#pragma unroll
        for (int ks = 0; ks < 9; ++ks) {
            bf16x8 f;
#pragma unroll
            for (int j = 0; j < 8; ++j) {
                int kg = ks * 32 + quad * 8 + j;
                float v;
                if (kg < 256)      v = W_rec[kg * H_ + cA];
                else if (kg < 264) v = W_in[(kg - 256) * H_ + cA];
                else               v = 0.f;
                f[j] = (short)pk2bf(v, v);
            }
            afrag[mt][ks] = f;
        }
    }

    // ---- x chunk loader: wave w loads batch row w (one float4/lane/chunk) ----
    const float* xrbase = x + (size_t)(r0 + w) * T_ * I_;
    const int xt = lane >> 1, xi0 = (lane & 1) * 4;
    float4 xr;

    xr = ((const float4*)xrbase)[lane];                      // chunk 0
    {
        int2 pk = make_int2(pk2bf(xr.x, xr.y), pk2bf(xr.z, xr.w));
        *reinterpret_cast<int2*>(&xstage[0][xt][w][xi0]) = pk;
    }
    xr = ((const float4*)(xrbase + (size_t)CH * I_))[lane];  // chunk 1 (convert at t=16)

    float hreg[4];
#pragma unroll
    for (int s = 0; s < 4; ++s) hreg[s] = 0.f;

    const short* hrow = &h_lds[row * LSTR + quad * 8];       // aliased (broadcast pairs)
    const f32x4 zacc = {0.f, 0.f, 0.f, 0.f};

    for (int t = 0; t < T_; ++t) {
        const int tc  = t & (CH - 1);
        const int c   = t >> 5;
        const int buf = c & 1;

        __syncthreads();  // barrier #1: h_t visible

        if (tc == 16) {   // convert held regs (chunk c+1) into idle buffer
            int2 pk = make_int2(pk2bf(xr.x, xr.y), pk2bf(xr.z, xr.w));
            *reinterpret_cast<int2*>(&xstage[buf ^ 1][xt][w][xi0]) = pk;
        }
        if (tc == 18) {   // issue loads for chunk c+2
            int cc = c + 2; if (cc > (T_ / CH) - 1) cc = (T_ / CH) - 1;
            xr = ((const float4*)(xrbase + (size_t)cc * CH * I_))[lane];
        }

        // ---- GEMM: 4 chains (2 mt x 2 k-halves), dep depth 5/4 ----
        const short* xb = (quad == 0) ? &xstage[buf][tc][row][0] : (const short*)zero16;
        f32x4 c0a = pbin0, c1a = pbin1, c0b = zacc, c1b = zacc;
#pragma unroll
        for (int ks = 0; ks < 4; ++ks) {
            bf16x8 bA = *reinterpret_cast<const bf16x8*>(hrow + ks * 32);
            bf16x8 bB = *reinterpret_cast<const bf16x8*>(hrow + (ks + 4) * 32);
            c0a = __builtin_amdgcn_mfma_f32_16x16x32_bf16(afrag[0][ks],     bA, c0a, 0, 0, 0);
            c1a = __builtin_amdgcn_mfma_f32_16x16x32_bf16(afrag[1][ks],     bA, c1a, 0, 0, 0);
            c0b = __builtin_amdgcn_mfma_f32_16x16x32_bf16(afrag[0][ks + 4], bB, c0b, 0, 0, 0);
            c1b = __builtin_amdgcn_mfma_f32_16x16x32_bf16(afrag[1][ks + 4], bB, c1b, 0, 0, 0);
        }
        {
            bf16x8 b8 = *reinterpret_cast<const bf16x8*>(xb);
            c0a = __builtin_amdgcn_mfma_f32_16x16x32_bf16(afrag[0][8], b8, c0a, 0, 0, 0);
            c1a = __builtin_amdgcn_mfma_f32_16x16x32_bf16(afrag[1][8], b8, c1a, 0, 0, 0);
        }

        // ---- this lane's assigned 4 values (half0: mt0, half1: mt1) ----
        f32x4 va;
#pragma unroll
        for (int r = 0; r < 4; ++r) {
            float v0 = c0a[r] + c0b[r];
            float v1 = c1a[r] + c1b[r];
            va[r] = half ? v1 : v0;
        }

        // ---- LN partial: 4-val fold + xor8 (pair) + xor16/32 (quads) ----
        float S  = (va[0] + va[1]) + (va[2] + va[3]);
        float SQ = fmaf(va[0], va[0], fmaf(va[1], va[1],
                   fmaf(va[2], va[2], va[3] * va[3])));
        S += __shfl_xor(S, 8, 64);   SQ += __shfl_xor(SQ, 8, 64);
        S += __shfl_xor(S, 16, 64);  SQ += __shfl_xor(SQ, 16, 64);
        S += __shfl_xor(S, 32, 64);  SQ += __shfl_xor(SQ, 32, 64);
        if (quad == 0 && half == 0) redt[row][w] = make_float2(S, SQ);

        __syncthreads();  // barrier #2: all wave partials in redt

        // ---- final stats: 4x ds_read_b128 (8 wave partials), aliased rows ----
        const float4* rrow = reinterpret_cast<const float4*>(&redt[row][0]);
        float4 q0 = rrow[0], q1 = rrow[1], q2 = rrow[2], q3 = rrow[3];
        float St  = ((q0.x + q0.z) + (q1.x + q1.z)) + ((q2.x + q2.z) + (q3.x + q3.z));
        float SQt = ((q0.y + q0.w) + (q1.y + q1.w)) + ((q2.y + q2.w) + (q3.y + q3.w));
        const float mu   = St * (1.f / 256.f);
        const float var  = fmaf(SQt, 1.f / 256.f, -mu * mu);
        const float rstd = __builtin_amdgcn_rsqf(var + EPS_);
        const float nmr  = -mu * rstd;

        // ---- f = tanh(LN*g1+b1); h = med3(h*decay + DT*f)  (4 values/lane) ----
#pragma unroll
        for (int s = 0; s < 4; ++s) {
            float tt = fmaf(va[s], rstd, nmr);
            float z2 = fmaf(tt, p_g1s[s], p_b1s[s]);            // 2z/ln2
            float e  = __builtin_amdgcn_exp2f(z2);              // e^(2z)
            float rc = __builtin_amdgcn_rcpf(e + 1.f);
            float fd = fmaf(rc, -2.f * DT_, DT_);               // DT*tanh(z)
            float h  = fmaf(hreg[s], p_decay[s], fd);
            hreg[s]  = __builtin_amdgcn_fmed3f(h, -10.f, 10.f);
        }
        // pack: every lane writes its 4 cols (b64) at its real row
        {
            int2 pk = make_int2(pk2bf(hreg[0], hreg[1]), pk2bf(hreg[2], hreg[3]));
            *reinterpret_cast<int2*>(&h_lds[row * LSTR + w * 32 + half * 16 + quad * 4]) = pk;
        }
    }

    // ---- epilogue: out = LN(h_T; g2,b2) @ head_w + head_b ----
    for (int i = tid; i < H_ * A_; i += 512) hw[i] = head_w[i];
    __syncthreads();

    float S2 = (hreg[0] + hreg[1]) + (hreg[2] + hreg[3]);
    float SQ2 = fmaf(hreg[0], hreg[0], fmaf(hreg[1], hreg[1],
                fmaf(hreg[2], hreg[2], hreg[3] * hreg[3])));
    S2 += __shfl_xor(S2, 8, 64);   SQ2 += __shfl_xor(SQ2, 8, 64);
    S2 += __shfl_xor(S2, 16, 64);  SQ2 += __shfl_xor(SQ2, 16, 64);
    S2 += __shfl_xor(S2, 32, 64);  SQ2 += __shfl_xor(SQ2, 32, 64);
    if (quad == 0 && half == 0) redt[row][w] = make_float2(S2, SQ2);
    __syncthreads();
    const float4* rrow = reinterpret_cast<const float4*>(&redt[row][0]);
    float4 q0 = rrow[0], q1 = rrow[1], q2 = rrow[2], q3 = rrow[3];
    float St  = ((q0.x + q0.z) + (q1.x + q1.z)) + ((q2.x + q2.z) + (q3.x + q3.z));
    float SQt = ((q0.y + q0.w) + (q1.y + q1.w)) + ((q2.y + q2.w) + (q3.y + q3.w));
    const float mu   = St * (1.f / 256.f);
    const float var  = fmaf(SQt, 1.f / 256.f, -mu * mu);
    const float rstd = __builtin_amdgcn_rsqf(var + EPS_);

    float pa[8];
#pragma unroll
    for (int a = 0; a < 8; ++a) pa[a] = 0.f;
#pragma unroll
    for (int s = 0; s < 4; ++s) {
        int c = w * 32 + half * 16 + quad * 4 + s;
        float lnh = (hreg[s] - mu) * rstd * g2[c] + beta2[c];
        float4 w0 = *reinterpret_cast<const float4*>(&hw[c * 8]);
        float4 w1 = *reinterpret_cast<const float4*>(&hw[c * 8 + 4]);
        pa[0] += lnh * w0.x; pa[1] += lnh * w0.y; pa[2] += lnh * w0.z; pa[3] += lnh * w0.w;
        pa[4] += lnh * w1.x; pa[5] += lnh * w1.y; pa[6] += lnh * w1.z; pa[7] += lnh * w1.w;
    }
#pragma unroll
    for (int a = 0; a < 8; ++a) {
        pa[a] += __shfl_xor(pa[a], 8, 64);
        pa[a] += __shfl_xor(pa[a], 16, 64);
        pa[a] += __shfl_xor(pa[a], 32, 64);
    }
    if (quad == 0 && half == 0) {
#pragma unroll
        for (int a = 0; a < 8; ++a) outp[w][row][a] = pa[a];
    }
    __syncthreads();
    if (tid < RB * A_) {
        int r = tid >> 3, a = tid & 7;
        float s = head_b[a];
#pragma unroll
        for (int ww = 0; ww < 8; ++ww) s += outp[ww][r][a];
        out[(size_t)(r0 + r) * A_ + a] = s;
    }
}

extern "C" void kernel_launch(void* const* d_in, const int* in_sizes, int n_in,
                              void* d_out, int out_size, void* d_ws, size_t ws_size,
                              hipStream_t stream) {
    const float* x         = (const float*)d_in[0];
    const float* W_in      = (const float*)d_in[1];
    const float* b_in      = (const float*)d_in[2];
    const float* tau_param = (const float*)d_in[3];
    const float* W_rec     = (const float*)d_in[4];
    const float* g1        = (const float*)d_in[5];
    const float* beta1     = (const float*)d_in[6];
    const float* g2        = (const float*)d_in[7];
    const float* beta2     = (const float*)d_in[8];
    const float* head_w    = (const float*)d_in[9];
    const float* head_b    = (const float*)d_in[10];
    float* out = (float*)d_out;

    liquid_kernel<<<128, 512, 0, stream>>>(x, W_in, b_in, tau_param, W_rec,
                                           g1, beta1, g2, beta2, head_w, head_b, out);
}